// Round 1
// baseline (1153.441 us; speedup 1.0000x reference)
//
#include <hip/hip_runtime.h>
#include <math.h>

// FilterShortRange: stable partition of 20M pairs by ||Rij|| <= 1.6, plus
// passthrough copies and n_valid.
//
// Output layout (float32, element offsets, P = n_pairs):
//   [0,     3P)  Rij_sr   (compacted, tail zeroed)
//   [3P,    4P)  idx_i_sr (compacted, tail -1)
//   [4P,    5P)  idx_j_sr (compacted, tail -1)
//   [5P,    8P)  Rij      (copy)
//   [8P,    9P)  idx_i    (copy, as float)
//   [9P,   10P)  idx_j    (copy, as float)
//   [10P]        n_valid  (as float)

#define BLOCK 256
#define VPT 4
#define CHUNK (BLOCK * VPT)
#define SCAN_T 1024

__device__ __forceinline__ bool short_mask(float x, float y, float z) {
    // Must bit-match jnp.linalg.norm(Rij,axis=-1) <= 1.6 in f32:
    // left-to-right sum, IEEE sqrt, compare vs 1.6f.
    float s = x * x + y * y + z * z;
    return sqrtf(s) <= 1.6f;
}

__global__ __launch_bounds__(BLOCK) void count_kernel(
    const float* __restrict__ Rij, int* __restrict__ counts, int P) {
    int b = blockIdx.x;
    int tid = threadIdx.x;
    int e0 = b * CHUNK + tid * VPT;
    int cnt = 0;
    if ((e0 + VPT <= P) && ((P & 3) == 0)) {
        const float4* R4 = (const float4*)Rij + (e0 * 3) / 4;
        float4 a = R4[0], c = R4[1], d = R4[2];
        cnt += short_mask(a.x, a.y, a.z);
        cnt += short_mask(a.w, c.x, c.y);
        cnt += short_mask(c.z, c.w, d.x);
        cnt += short_mask(d.y, d.z, d.w);
    } else {
        for (int j = 0; j < VPT; ++j) {
            int p = e0 + j;
            if (p < P) {
                float x = Rij[3 * p], y = Rij[3 * p + 1], z = Rij[3 * p + 2];
                cnt += short_mask(x, y, z);
            }
        }
    }
    // wave reduce (64 lanes)
    for (int off = 32; off > 0; off >>= 1) cnt += __shfl_down(cnt, off);
    __shared__ int sm[BLOCK / 64];
    int lane = tid & 63, wid = tid >> 6;
    if (lane == 0) sm[wid] = cnt;
    __syncthreads();
    if (tid == 0) {
        int t = 0;
        for (int w = 0; w < BLOCK / 64; ++w) t += sm[w];
        counts[b] = t;
    }
}

__global__ __launch_bounds__(SCAN_T) void scan_kernel(
    const int* __restrict__ counts, int* __restrict__ offsets, int nb,
    int* __restrict__ nvalid_ws, float* __restrict__ nvalid_out) {
    __shared__ int sm[SCAN_T];
    __shared__ int carry_s;
    int tid = threadIdx.x;
    if (tid == 0) carry_s = 0;
    __syncthreads();
    for (int start = 0; start < nb; start += SCAN_T) {
        int i = start + tid;
        int v = (i < nb) ? counts[i] : 0;
        sm[tid] = v;
        __syncthreads();
        for (int off = 1; off < SCAN_T; off <<= 1) {
            int y = (tid >= off) ? sm[tid - off] : 0;
            __syncthreads();
            sm[tid] += y;
            __syncthreads();
        }
        int incl = sm[tid];
        int carry = carry_s;          // stable: last written before prior sync
        if (i < nb) offsets[i] = carry + incl - v;
        __syncthreads();
        if (tid == 0) carry_s = carry + sm[SCAN_T - 1];
        __syncthreads();
    }
    if (tid == 0) {
        nvalid_ws[0] = carry_s;
        nvalid_out[0] = (float)carry_s;
    }
}

__global__ __launch_bounds__(BLOCK) void scatter_kernel(
    const float* __restrict__ Rij, const int* __restrict__ idx_i,
    const int* __restrict__ idx_j, const int* __restrict__ offsets,
    const int* __restrict__ nvalid_ws, float* __restrict__ out, int P) {
    int b = blockIdx.x;
    int tid = threadIdx.x;
    int lane = tid & 63, wid = tid >> 6;
    int e0 = b * CHUNK + tid * VPT;
    int nvalid = nvalid_ws[0];

    float x[VPT], y[VPT], z[VPT];
    int ii[VPT], jj[VPT];
    bool m[VPT], inr[VPT];

    bool fullvec = (e0 + VPT <= P) && ((P & 3) == 0);
    if (fullvec) {
        const float4* R4 = (const float4*)Rij + (e0 * 3) / 4;
        float4 a = R4[0], c = R4[1], d = R4[2];
        x[0] = a.x; y[0] = a.y; z[0] = a.z;
        x[1] = a.w; y[1] = c.x; z[1] = c.y;
        x[2] = c.z; y[2] = c.w; z[2] = d.x;
        x[3] = d.y; y[3] = d.z; z[3] = d.w;
        int4 vi = *((const int4*)idx_i + e0 / 4);
        int4 vj = *((const int4*)idx_j + e0 / 4);
        ii[0] = vi.x; ii[1] = vi.y; ii[2] = vi.z; ii[3] = vi.w;
        jj[0] = vj.x; jj[1] = vj.y; jj[2] = vj.z; jj[3] = vj.w;
        for (int j = 0; j < VPT; ++j) {
            inr[j] = true;
            m[j] = short_mask(x[j], y[j], z[j]);
        }
        // long-range passthrough, vectorized
        float4* lrR = (float4*)(out + 5LL * P) + (e0 * 3) / 4;
        lrR[0] = a; lrR[1] = c; lrR[2] = d;
        float4 fi = make_float4((float)ii[0], (float)ii[1], (float)ii[2], (float)ii[3]);
        float4 fj = make_float4((float)jj[0], (float)jj[1], (float)jj[2], (float)jj[3]);
        *((float4*)(out + 8LL * P) + e0 / 4) = fi;
        *((float4*)(out + 9LL * P) + e0 / 4) = fj;
    } else {
        for (int j = 0; j < VPT; ++j) {
            int p = e0 + j;
            inr[j] = (p < P);
            if (inr[j]) {
                x[j] = Rij[3 * p]; y[j] = Rij[3 * p + 1]; z[j] = Rij[3 * p + 2];
                ii[j] = idx_i[p]; jj[j] = idx_j[p];
                m[j] = short_mask(x[j], y[j], z[j]);
                out[5LL * P + 3 * p] = x[j];
                out[5LL * P + 3 * p + 1] = y[j];
                out[5LL * P + 3 * p + 2] = z[j];
                out[8LL * P + p] = (float)ii[j];
                out[9LL * P + p] = (float)jj[j];
            } else {
                m[j] = false;
            }
        }
    }

    int cnt = 0;
    for (int j = 0; j < VPT; ++j) cnt += (inr[j] && m[j]);

    // wave-exclusive scan of per-thread counts (64 lanes)
    int xs = cnt;
    for (int off = 1; off < 64; off <<= 1) {
        int yv = __shfl_up(xs, off);
        if (lane >= off) xs += yv;
    }
    int waveExcl = xs - cnt;
    __shared__ int wsum[BLOCK / 64];
    if (lane == 63) wsum[wid] = xs;
    __syncthreads();
    int wpre = 0;
    for (int w = 0; w < wid; ++w) wpre += wsum[w];

    int base = offsets[b] + wpre + waveExcl;  // global valid rank of this thread's first element
    int thrPre = 0;
    for (int j = 0; j < VPT; ++j) {
        if (!inr[j]) continue;
        int p = e0 + j;
        int v = base + thrPre;  // # valid strictly before p, globally
        if (m[j]) {
            out[3 * v] = x[j];
            out[3 * v + 1] = y[j];
            out[3 * v + 2] = z[j];
            out[3LL * P + v] = (float)ii[j];
            out[4LL * P + v] = (float)jj[j];
            ++thrPre;
        } else {
            int dst = nvalid + (p - v);  // bijection onto tail slots
            out[3 * dst] = 0.0f;
            out[3 * dst + 1] = 0.0f;
            out[3 * dst + 2] = 0.0f;
            out[3LL * P + dst] = -1.0f;
            out[4LL * P + dst] = -1.0f;
        }
    }
}

extern "C" void kernel_launch(void* const* d_in, const int* in_sizes, int n_in,
                              void* d_out, int out_size, void* d_ws, size_t ws_size,
                              hipStream_t stream) {
    const float* Rij = (const float*)d_in[0];
    const int* idx_i = (const int*)d_in[1];
    const int* idx_j = (const int*)d_in[2];
    int P = in_sizes[1];
    float* out = (float*)d_out;

    int nb = (P + CHUNK - 1) / CHUNK;
    int* counts = (int*)d_ws;
    int* offsets = counts + nb;
    int* nvalid_ws = offsets + nb;

    count_kernel<<<nb, BLOCK, 0, stream>>>(Rij, counts, P);
    scan_kernel<<<1, SCAN_T, 0, stream>>>(counts, offsets, nb, nvalid_ws,
                                          out + 10LL * P);
    scatter_kernel<<<nb, BLOCK, 0, stream>>>(Rij, idx_i, idx_j, offsets,
                                             nvalid_ws, out, P);
}